// Round 6
// baseline (1910.104 us; speedup 1.0000x reference)
//
#include <hip/hip_runtime.h>
#include <hip/hip_bf16.h>

#define NXD 512
#define NYD 512
#define TD 5
#define BD 4
#define HIDD 64
#define PLANE (NXD*NYD)      /* 262144 */
#define VOL (TD*PLANE)       /* 1310720 */
#define CBLK 1024            /* cost blocks per batch */

typedef __bf16 bf16x8 __attribute__((ext_vector_type(8)));
typedef __bf16 bf16x4 __attribute__((ext_vector_type(4)));
typedef float  f32x4  __attribute__((ext_vector_type(4)));

// LDS strides: sx 16 B/pixel; sh(strip) 72 B/pixel (bank stride 18 -> the 16
// l15 lanes hit 16 distinct banks; b128 at 8-cycle floor).
#define SX_PS 16
#define SH_PS 72

// W1r: [kt=3][ch=64][32 bf16]   k = tap*8 + c8   (taps 9..11 zero-padded)
// W2r: [h=2][tap=9][out=16][32] k(within half) = c32; out 5..15 zero
#define W1R_ELEMS (3*64*32)   /* 6144 */
#define W2R_ELEMS (2*9*16*32) /* 9216 */

__global__ __launch_bounds__(256)
void prep_weights(const float* __restrict__ W1, const float* __restrict__ W2,
                  __bf16* __restrict__ W1r, __bf16* __restrict__ W2r)
{
    int id = blockIdx.x * 256 + threadIdx.x;
    if (id < W1R_ELEMS) {
        int kt  = id >> 11;
        int rem = id & 2047;
        int n   = rem >> 5;
        int kk  = rem & 31;
        int k   = kt * 32 + kk;
        int tap = k >> 3, c = k & 7;
        float v = 0.f;
        if (tap <= 8 && c < 5)
            v = W1[(n * 5 + c) * 9 + tap];      // W1 [64][5][3][3]
        W1r[id] = (__bf16)v;
    } else if (id < W1R_ELEMS + W2R_ELEMS) {
        int id2 = id - W1R_ELEMS;
        int h    = id2 / 4608;
        int rem  = id2 - h * 4608;
        int tap  = rem >> 9;
        int rem2 = rem & 511;
        int n    = rem2 >> 5;
        int c    = rem2 & 31;
        float v = 0.f;
        if (n < 5)
            v = W2[(n * HIDD + h * 32 + c) * 9 + tap];  // W2 [5][64][3][3]
        W2r[id2] = (__bf16)v;
    }
}

// ---------------------------------------------------------------------------
// Fused phi (+ optional cost of its INPUT, pure-global).
// A = weights (m = channels), B = activations (n = pixels).
// Per half (32 ch), per strip s in {0,1} (h rows s*8 .. s*8+9):
//   conv1: 12 n-tiles (180 real px of 192), wave does 3; h -> sh strip buffer.
//   conv2: out rows s*8..s*8+7; wave owns rows s*8+wv*2+{0,1};
//          row-sum loop r=0..3 reads each (row,shift) ONCE (12 reads/18 MFMA).
// LDS: sx 21x20x16 = 6720 B, sh 180x72 = 12960 B -> 8 blocks/CU.
// ---------------------------------------------------------------------------
__global__ __launch_bounds__(256, 8)
void phi_mfma(const float* __restrict__ xin,
              const __bf16* __restrict__ W1r, const __bf16* __restrict__ W2r,
              const float* __restrict__ b1, const float* __restrict__ b2,
              const float* __restrict__ gt, const float* __restrict__ yobs,
              const int* __restrict__ mask,
              float* __restrict__ xout, float* __restrict__ cpart, int blend)
{
    __shared__ __align__(16) char sx[21 * 20 * SX_PS];  // 6720 B
    __shared__ __align__(16) char sh[180 * SH_PS];      // 12960 B
    __shared__ float red[3][4];

    const int tid   = threadIdx.x;
    const int wv    = tid >> 6;
    const int lane  = tid & 63;
    const int l15   = lane & 15;
    const int quad  = lane >> 4;
    const int b     = blockIdx.z;
    const int gx0   = blockIdx.x * 16;
    const int gy0   = blockIdx.y * 16;
    const float* xb = xin + (size_t)b * VOL;

    // ---- stage x tile 21x20 (halo 2): one b128 write per pixel ----
    for (int p = tid; p < 420; p += 256) {
        const int u  = p / 20;
        const int v  = p - u * 20;
        const int gx = gx0 + u - 2;
        const int gy = gy0 + v - 2;
        bf16x8 pix = {(__bf16)0.f,(__bf16)0.f,(__bf16)0.f,(__bf16)0.f,
                      (__bf16)0.f,(__bf16)0.f,(__bf16)0.f,(__bf16)0.f};
        if (gx >= 0 && gx < NXD && gy >= 0 && gy < NYD) {
            const float* src = xb + (size_t)gx * NYD + gy;
            #pragma unroll
            for (int c = 0; c < TD; ++c) pix[c] = (__bf16)src[(size_t)c * PLANE];
        }
        *(bf16x8*)(sx + p * SX_PS) = pix;
    }

    // ---- fused cost of INPUT x, pure-global (overlaps staging; no barrier) ----
    if (cpart) {
        const int ti = tid >> 4, tj = tid & 15;
        const int gx = gx0 + ti, gy = gy0 + tj;
        const size_t gbase = (size_t)b * VOL + (size_t)gx * NYD + gy;
        float mse = 0.f, dyv = 0.f, q = 0.f;
        #pragma unroll
        for (int c = 0; c < TD; ++c) {
            const size_t gi = gbase + (size_t)c * PLANE;
            const float vv = xin[gi];
            const float g  = gt[gi];
            const float yo = yobs[gi];
            const int   m  = mask[gi];
            mse += (g - vv) * (g - vv);
            float d = vv - yo;
            if (m) dyv += d * d;
            float nb = 0.f;
            if (c < TD - 1)  nb += xin[gi + PLANE];
            if (gx < NXD - 1) nb += xin[gi + NYD];
            if (gy < NYD - 1) nb += xin[gi + 1];
            q += 6.01f * vv * vv - 2.f * vv * nb;
        }
        #pragma unroll
        for (int off = 32; off > 0; off >>= 1) {
            mse += __shfl_xor(mse, off, 64);
            dyv += __shfl_xor(dyv, off, 64);
            q   += __shfl_xor(q,   off, 64);
        }
        if (lane == 0) { red[0][wv] = mse; red[1][wv] = dyv; red[2][wv] = q; }
    }
    __syncthreads();  // sx ready (+ red ready)
    if (cpart && tid == 0) {
        float* pp = cpart + ((size_t)b * 1024 + blockIdx.y * 32 + blockIdx.x) * 3;
        pp[0] = red[0][0] + red[0][1] + red[0][2] + red[0][3];
        pp[1] = red[1][0] + red[1][1] + red[1][2] + red[1][3];
        pp[2] = red[2][0] + red[2][1] + red[2][2] + red[2][3];
    }

    f32x4 acc2[2][2] = {{{0.f,0.f,0.f,0.f},{0.f,0.f,0.f,0.f}},
                        {{0.f,0.f,0.f,0.f},{0.f,0.f,0.f,0.f}}};

    for (int half = 0; half < 2; ++half) {
        // ---- conv1 A (weight) frags + bias ----
        bf16x8 A1[2][3];
        f32x4  bias1[2];
        #pragma unroll
        for (int mt = 0; mt < 2; ++mt) {
            bias1[mt] = *(const f32x4*)(b1 + half * 32 + mt * 16 + quad * 4);
            #pragma unroll
            for (int kt = 0; kt < 3; ++kt)
                A1[mt][kt] = *(const bf16x8*)(W1r +
                    ((size_t)(kt * 64 + half * 32 + mt * 16 + l15) * 32 + quad * 8));
        }
        // ---- conv2 A (weight) frags for this half ----
        bf16x8 A2[9];
        #pragma unroll
        for (int tap = 0; tap < 9; ++tap)
            A2[tap] = *(const bf16x8*)(W2r +
                ((size_t)((half * 9 + tap) * 16 + l15) * 32 + quad * 8));

        for (int s = 0; s < 2; ++s) {
            if (half | s) __syncthreads();  // prev conv2 reads of sh done

            // ---- conv1 strip: 3 n-tiles per wave ----
            #pragma unroll
            for (int nt = 0; nt < 3; ++nt) {
                const int q  = (wv * 3 + nt) * 16 + l15;  // local px in 192-space
                const int il = q / 18;
                const int j  = q - 18 * il;
                const int rowb = (s * 8 + il) * 20 + j;
                bf16x8 Bx[3];
                #pragma unroll
                for (int kt = 0; kt < 3; ++kt) {
                    int tap = kt * 4 + quad;
                    if (tap > 8) tap = 8;     // pad taps: weights zero, clamp addr
                    Bx[kt] = *(const bf16x8*)(sx + (rowb + (tap / 3) * 20 + tap % 3) * SX_PS);
                }
                #pragma unroll
                for (int mt = 0; mt < 2; ++mt) {
                    f32x4 a = {0.f, 0.f, 0.f, 0.f};
                    #pragma unroll
                    for (int kt = 0; kt < 3; ++kt)
                        a = __builtin_amdgcn_mfma_f32_16x16x32_bf16(
                                A1[mt][kt], Bx[kt], a, 0, 0, 0);
                    if (q < 180) {
                        bf16x4 hv;
                        #pragma unroll
                        for (int r = 0; r < 4; ++r)
                            hv[r] = (__bf16)fmaxf(a[r] + bias1[mt][r], 0.f);
                        *(bf16x4*)(sh + q * SH_PS + (mt * 16 + quad * 4) * 2) = hv;
                    }
                }
            }
            __syncthreads();

            // ---- conv2 strip: row-sum loop, each (row,shift) read once ----
            #pragma unroll
            for (int r = 0; r < 4; ++r) {
                const int rowoff = ((wv * 2 + r) * 18 + l15) * SH_PS + quad * 16;
                #pragma unroll
                for (int tx = 0; tx < 3; ++tx) {
                    const bf16x8 B = *(const bf16x8*)(sh + rowoff + tx * SH_PS);
                    if (r < 3)
                        acc2[s][0] = __builtin_amdgcn_mfma_f32_16x16x32_bf16(
                                         A2[r * 3 + tx], B, acc2[s][0], 0, 0, 0);
                    if (r >= 1)
                        acc2[s][1] = __builtin_amdgcn_mfma_f32_16x16x32_bf16(
                                         A2[(r - 1) * 3 + tx], B, acc2[s][1], 0, 0, 0);
                }
            }
        }
    }

    // ---- epilogue: D row = out-channel (quad*4+reg), col = pixel (l15) ----
    #pragma unroll
    for (int s = 0; s < 2; ++s) {
        #pragma unroll
        for (int m = 0; m < 2; ++m) {
            const int ti2 = s * 8 + wv * 2 + m;
            const size_t rowoff = (size_t)b * VOL + (size_t)(gx0 + ti2) * NYD + (gy0 + l15);
            #pragma unroll
            for (int r = 0; r < 4; ++r) {
                const int ch = quad * 4 + r;
                if (ch < TD) {
                    const size_t off = rowoff + (size_t)ch * PLANE;
                    float o = acc2[s][m][r] + b2[ch];
                    if (blend && mask[off]) o = yobs[off];
                    xout[off] = o;
                }
            }
        }
    }
}

// ---------------------------------------------------------------------------
// Standalone cost (for x5 only). Grid (1024, BD); 5 elems/thread.
// ---------------------------------------------------------------------------
__global__ __launch_bounds__(256)
void cost_kernel(const float* __restrict__ x, const float* __restrict__ gt,
                 const float* __restrict__ yobs, const int* __restrict__ mask,
                 float* __restrict__ partial)
{
    const int b  = blockIdx.y;
    const size_t bbase = (size_t)b * VOL;

    float mse = 0.f, dy = 0.f, q = 0.f;
    for (int idx = blockIdx.x * 256 + threadIdx.x; idx < VOL; idx += CBLK * 256) {
        const size_t gi = bbase + idx;
        const int t   = idx / PLANE;
        const int rem = idx - t * PLANE;
        const int i   = rem / NYD;
        const int j   = rem - i * NYD;

        const float v  = x[gi];
        const float g  = gt[gi];
        const float yo = yobs[gi];
        const int   m  = mask[gi];

        mse += (g - v) * (g - v);
        float d = v - yo;
        if (m) dy += d * d;
        float qq = 6.01f * v * v;
        if (t < TD - 1)  qq -= 2.f * v * x[gi + PLANE];
        if (i < NXD - 1) qq -= 2.f * v * x[gi + NYD];
        if (j < NYD - 1) qq -= 2.f * v * x[gi + 1];
        q += qq;
    }

    #pragma unroll
    for (int off = 32; off > 0; off >>= 1) {
        mse += __shfl_xor(mse, off, 64);
        dy  += __shfl_xor(dy,  off, 64);
        q   += __shfl_xor(q,   off, 64);
    }
    __shared__ float red[3][4];
    const int wave = threadIdx.x >> 6;
    const int lane = threadIdx.x & 63;
    if (lane == 0) { red[0][wave] = mse; red[1][wave] = dy; red[2][wave] = q; }
    __syncthreads();
    if (threadIdx.x == 0) {
        float* p = partial + ((size_t)b * CBLK + blockIdx.x) * 3;
        p[0] = red[0][0] + red[0][1] + red[0][2] + red[0][3];
        p[1] = red[1][0] + red[1][1] + red[1][2] + red[1][3];
        p[2] = red[2][0] + red[2][1] + red[2][2] + red[2][3];
    }
}

// cpart layout: [row r=0..4][b=0..3][1024][3].  out cmp_loss [B=4][5][2].
__global__ __launch_bounds__(256)
void finalize_kernel(const float* __restrict__ cpart,
                     float* __restrict__ out)
{
    const int r = blockIdx.x / BD;
    const int b = blockIdx.x - r * BD;
    const float* base = cpart + ((size_t)r * BD + b) * 1024 * 3;
    float mse = 0.f, dy = 0.f, q = 0.f;
    for (int k = threadIdx.x; k < 1024; k += 256) {
        mse += base[k * 3 + 0];
        dy  += base[k * 3 + 1];
        q   += base[k * 3 + 2];
    }
    #pragma unroll
    for (int off = 32; off > 0; off >>= 1) {
        mse += __shfl_xor(mse, off, 64);
        dy  += __shfl_xor(dy,  off, 64);
        q   += __shfl_xor(q,   off, 64);
    }
    __shared__ float red[3][4];
    const int wave = threadIdx.x >> 6;
    const int lane = threadIdx.x & 63;
    if (lane == 0) { red[0][wave] = mse; red[1][wave] = dy; red[2][wave] = q; }
    __syncthreads();
    if (threadIdx.x == 0) {
        float m  = red[0][0] + red[0][1] + red[0][2] + red[0][3];
        float d  = red[1][0] + red[1][1] + red[1][2] + red[1][3];
        float qq = red[2][0] + red[2][1] + red[2][2] + red[2][3];
        out[b * 10 + r * 2 + 0] = m / (float)VOL;
        out[b * 10 + r * 2 + 1] = 1000.f * d + qq;
    }
}

extern "C" void kernel_launch(void* const* d_in, const int* in_sizes, int n_in,
                              void* d_out, int out_size, void* d_ws, size_t ws_size,
                              hipStream_t stream)
{
    const float* gt   = (const float*)d_in[0];
    const float* x0   = (const float*)d_in[1];
    const float* yobs = (const float*)d_in[2];
    const int*   mask = (const int*)d_in[3];
    const float* W1   = (const float*)d_in[4];
    const float* b1   = (const float*)d_in[5];
    const float* W2   = (const float*)d_in[6];
    const float* b2   = (const float*)d_in[7];

    float* out_x    = (float*)d_out;
    float* out_loss = out_x + (size_t)BD * VOL;

    float* wsA      = (float*)d_ws;                   // ping buffer (21 MB)
    float* cpart    = wsA + (size_t)BD * VOL;         // 5*4*1024*3 floats
    __bf16* W1r     = (__bf16*)(cpart + 5 * BD * 1024 * 3);
    __bf16* W2r     = W1r + W1R_ELEMS;
    const size_t PROW = (size_t)BD * 1024 * 3;        // per-row stride

    dim3 pgrid(NXD / 16, NYD / 16, BD), pblock(256);
    dim3 cgrid(CBLK, BD), cblock(256);

    prep_weights<<<dim3(60), dim3(256), 0, stream>>>(W1, W2, W1r, W2r);

    // x1..x4 blended; each phi also computes cost of its INPUT (rows 0..3)
    phi_mfma<<<pgrid, pblock, 0, stream>>>(x0,   W1r, W2r, b1, b2, gt, yobs, mask, out_x, cpart + 0 * PROW, 1);
    phi_mfma<<<pgrid, pblock, 0, stream>>>(out_x,W1r, W2r, b1, b2, gt, yobs, mask, wsA,   cpart + 1 * PROW, 1);
    phi_mfma<<<pgrid, pblock, 0, stream>>>(wsA,  W1r, W2r, b1, b2, gt, yobs, mask, out_x, cpart + 2 * PROW, 1);
    phi_mfma<<<pgrid, pblock, 0, stream>>>(out_x,W1r, W2r, b1, b2, gt, yobs, mask, wsA,   cpart + 3 * PROW, 1);
    // x5 = phi(x4), no blend, no fused cost
    phi_mfma<<<pgrid, pblock, 0, stream>>>(wsA,  W1r, W2r, b1, b2, gt, yobs, mask, out_x, nullptr, 0);
    // cost(x5) -> row 4
    cost_kernel<<<cgrid, cblock, 0, stream>>>(out_x, gt, yobs, mask, cpart + 4 * PROW);

    finalize_kernel<<<dim3(5 * BD), dim3(256), 0, stream>>>(cpart, out_loss);
}

// Round 7
// 1495.950 us; speedup vs baseline: 1.2769x; 1.2769x over previous
//
#include <hip/hip_runtime.h>
#include <hip/hip_bf16.h>

#define NXD 512
#define NYD 512
#define TD 5
#define BD 4
#define HIDD 64
#define PLANE (NXD*NYD)      /* 262144 */
#define VOL (TD*PLANE)       /* 1310720 */
#define CBLK 1024            /* cost blocks per batch */

typedef __bf16 bf16x8 __attribute__((ext_vector_type(8)));
typedef __bf16 bf16x4 __attribute__((ext_vector_type(4)));
typedef float  f32x4  __attribute__((ext_vector_type(4)));

// LDS strides: sx 16 B/pixel; sh(strip) 72 B/pixel.
#define SX_PS 16
#define SH_PS 72

// W1r: [kt=3][ch=64][32 bf16]   k = tap*8 + c8   (taps 9..11 zero-padded)
// W2r: [h=2][tap=9][out=16][32] k(within half) = c32; out 5..15 zero
#define W1R_ELEMS (3*64*32)   /* 6144 */
#define W2R_ELEMS (2*9*16*32) /* 9216 */

__global__ __launch_bounds__(256)
void prep_weights(const float* __restrict__ W1, const float* __restrict__ W2,
                  __bf16* __restrict__ W1r, __bf16* __restrict__ W2r)
{
    int id = blockIdx.x * 256 + threadIdx.x;
    if (id < W1R_ELEMS) {
        int kt  = id >> 11;
        int rem = id & 2047;
        int n   = rem >> 5;
        int kk  = rem & 31;
        int k   = kt * 32 + kk;
        int tap = k >> 3, c = k & 7;
        float v = 0.f;
        if (tap <= 8 && c < 5)
            v = W1[(n * 5 + c) * 9 + tap];      // W1 [64][5][3][3]
        W1r[id] = (__bf16)v;
    } else if (id < W1R_ELEMS + W2R_ELEMS) {
        int id2 = id - W1R_ELEMS;
        int h    = id2 / 4608;
        int rem  = id2 - h * 4608;
        int tap  = rem >> 9;
        int rem2 = rem & 511;
        int n    = rem2 >> 5;
        int c    = rem2 & 31;
        float v = 0.f;
        if (n < 5)
            v = W2[(n * HIDD + h * 32 + c) * 9 + tap];  // W2 [5][64][3][3]
        W2r[id2] = (__bf16)v;
    }
}

// ---------------------------------------------------------------------------
// Fused phi (+ optional cost of its INPUT, pure-global).
// A = weights (m = channels), B = activations (n = pixels).
// Per half (32 ch), per strip s in {0,1} (h rows s*8 .. s*8+9):
//   conv1: 12 n-tiles (180 real px of 192), wave does 3; h -> sh strip buffer.
//   conv2: out rows s*8..s*8+7; wave owns rows s*8+wv*2+{0,1}.
// LDS: sx 21x20x16 = 6720 B, sh 180x72 = 12960 B.
// launch_bounds(256,6): VGPR cap 84 -- round-6's (256,8) cap of 64 caused
// catastrophic scratch spill (1.46 GB HBM traffic/dispatch). 6 blocks/CU.
// ---------------------------------------------------------------------------
__global__ __launch_bounds__(256, 6)
void phi_mfma(const float* __restrict__ xin,
              const __bf16* __restrict__ W1r, const __bf16* __restrict__ W2r,
              const float* __restrict__ b1, const float* __restrict__ b2,
              const float* __restrict__ gt, const float* __restrict__ yobs,
              const int* __restrict__ mask,
              float* __restrict__ xout, float* __restrict__ cpart, int blend)
{
    __shared__ __align__(16) char sx[21 * 20 * SX_PS];  // 6720 B
    __shared__ __align__(16) char sh[180 * SH_PS];      // 12960 B
    __shared__ float red[3][4];

    const int tid   = threadIdx.x;
    const int wv    = tid >> 6;
    const int lane  = tid & 63;
    const int l15   = lane & 15;
    const int quad  = lane >> 4;
    const int b     = blockIdx.z;
    const int gx0   = blockIdx.x * 16;
    const int gy0   = blockIdx.y * 16;
    const float* xb = xin + (size_t)b * VOL;

    // ---- stage x tile 21x20 (halo 2): one b128 write per pixel ----
    for (int p = tid; p < 420; p += 256) {
        const int u  = p / 20;
        const int v  = p - u * 20;
        const int gx = gx0 + u - 2;
        const int gy = gy0 + v - 2;
        bf16x8 pix = {(__bf16)0.f,(__bf16)0.f,(__bf16)0.f,(__bf16)0.f,
                      (__bf16)0.f,(__bf16)0.f,(__bf16)0.f,(__bf16)0.f};
        if (gx >= 0 && gx < NXD && gy >= 0 && gy < NYD) {
            const float* src = xb + (size_t)gx * NYD + gy;
            #pragma unroll
            for (int c = 0; c < TD; ++c) pix[c] = (__bf16)src[(size_t)c * PLANE];
        }
        *(bf16x8*)(sx + p * SX_PS) = pix;
    }

    // ---- fused cost of INPUT x, pure-global (overlaps staging) ----
    if (cpart) {
        const int ti = tid >> 4, tj = tid & 15;
        const int gx = gx0 + ti, gy = gy0 + tj;
        const size_t gbase = (size_t)b * VOL + (size_t)gx * NYD + gy;
        float mse = 0.f, dyv = 0.f, q = 0.f;
        #pragma unroll
        for (int c = 0; c < TD; ++c) {
            const size_t gi = gbase + (size_t)c * PLANE;
            const float vv = xin[gi];
            const float g  = gt[gi];
            const float yo = yobs[gi];
            const int   m  = mask[gi];
            mse += (g - vv) * (g - vv);
            float d = vv - yo;
            if (m) dyv += d * d;
            float nb = 0.f;
            if (c < TD - 1)  nb += xin[gi + PLANE];
            if (gx < NXD - 1) nb += xin[gi + NYD];
            if (gy < NYD - 1) nb += xin[gi + 1];
            q += 6.01f * vv * vv - 2.f * vv * nb;
        }
        #pragma unroll
        for (int off = 32; off > 0; off >>= 1) {
            mse += __shfl_xor(mse, off, 64);
            dyv += __shfl_xor(dyv, off, 64);
            q   += __shfl_xor(q,   off, 64);
        }
        if (lane == 0) { red[0][wv] = mse; red[1][wv] = dyv; red[2][wv] = q; }
    }
    __syncthreads();  // sx ready (+ red ready)
    if (cpart && tid == 0) {
        float* pp = cpart + ((size_t)b * 1024 + blockIdx.y * 32 + blockIdx.x) * 3;
        pp[0] = red[0][0] + red[0][1] + red[0][2] + red[0][3];
        pp[1] = red[1][0] + red[1][1] + red[1][2] + red[1][3];
        pp[2] = red[2][0] + red[2][1] + red[2][2] + red[2][3];
    }

    f32x4 acc2[2][2] = {{{0.f,0.f,0.f,0.f},{0.f,0.f,0.f,0.f}},
                        {{0.f,0.f,0.f,0.f},{0.f,0.f,0.f,0.f}}};

    for (int half = 0; half < 2; ++half) {
        // ---- conv1 A (weight) frags + bias ----
        bf16x8 A1[2][3];
        f32x4  bias1[2];
        #pragma unroll
        for (int mt = 0; mt < 2; ++mt) {
            bias1[mt] = *(const f32x4*)(b1 + half * 32 + mt * 16 + quad * 4);
            #pragma unroll
            for (int kt = 0; kt < 3; ++kt)
                A1[mt][kt] = *(const bf16x8*)(W1r +
                    ((size_t)(kt * 64 + half * 32 + mt * 16 + l15) * 32 + quad * 8));
        }
        // ---- conv2 A (weight) frags for this half ----
        bf16x8 A2[9];
        #pragma unroll
        for (int tap = 0; tap < 9; ++tap)
            A2[tap] = *(const bf16x8*)(W2r +
                ((size_t)((half * 9 + tap) * 16 + l15) * 32 + quad * 8));

        for (int s = 0; s < 2; ++s) {
            if (half | s) __syncthreads();  // prev conv2 reads of sh done

            // ---- conv1 strip: 3 n-tiles per wave ----
            #pragma unroll
            for (int nt = 0; nt < 3; ++nt) {
                const int q  = (wv * 3 + nt) * 16 + l15;  // local px in 192-space
                const int il = q / 18;
                const int j  = q - 18 * il;
                const int rowb = (s * 8 + il) * 20 + j;
                bf16x8 Bx[3];
                #pragma unroll
                for (int kt = 0; kt < 3; ++kt) {
                    int tap = kt * 4 + quad;
                    if (tap > 8) tap = 8;     // pad taps: weights zero, clamp addr
                    Bx[kt] = *(const bf16x8*)(sx + (rowb + (tap / 3) * 20 + tap % 3) * SX_PS);
                }
                #pragma unroll
                for (int mt = 0; mt < 2; ++mt) {
                    f32x4 a = {0.f, 0.f, 0.f, 0.f};
                    #pragma unroll
                    for (int kt = 0; kt < 3; ++kt)
                        a = __builtin_amdgcn_mfma_f32_16x16x32_bf16(
                                A1[mt][kt], Bx[kt], a, 0, 0, 0);
                    if (q < 180) {
                        bf16x4 hv;
                        #pragma unroll
                        for (int r = 0; r < 4; ++r)
                            hv[r] = (__bf16)fmaxf(a[r] + bias1[mt][r], 0.f);
                        *(bf16x4*)(sh + q * SH_PS + (mt * 16 + quad * 4) * 2) = hv;
                    }
                }
            }
            __syncthreads();

            // ---- conv2 strip: row-sum loop, each (row,shift) read once ----
            #pragma unroll
            for (int r = 0; r < 4; ++r) {
                const int rowoff = ((wv * 2 + r) * 18 + l15) * SH_PS + quad * 16;
                #pragma unroll
                for (int tx = 0; tx < 3; ++tx) {
                    const bf16x8 B = *(const bf16x8*)(sh + rowoff + tx * SH_PS);
                    if (r < 3)
                        acc2[s][0] = __builtin_amdgcn_mfma_f32_16x16x32_bf16(
                                         A2[r * 3 + tx], B, acc2[s][0], 0, 0, 0);
                    if (r >= 1)
                        acc2[s][1] = __builtin_amdgcn_mfma_f32_16x16x32_bf16(
                                         A2[(r - 1) * 3 + tx], B, acc2[s][1], 0, 0, 0);
                }
            }
        }
    }

    // ---- epilogue: D row = out-channel (quad*4+reg), col = pixel (l15) ----
    #pragma unroll
    for (int s = 0; s < 2; ++s) {
        #pragma unroll
        for (int m = 0; m < 2; ++m) {
            const int ti2 = s * 8 + wv * 2 + m;
            const size_t rowoff = (size_t)b * VOL + (size_t)(gx0 + ti2) * NYD + (gy0 + l15);
            #pragma unroll
            for (int r = 0; r < 4; ++r) {
                const int ch = quad * 4 + r;
                if (ch < TD) {
                    const size_t off = rowoff + (size_t)ch * PLANE;
                    float o = acc2[s][m][r] + b2[ch];
                    if (blend && mask[off]) o = yobs[off];
                    xout[off] = o;
                }
            }
        }
    }
}

// ---------------------------------------------------------------------------
// Standalone cost (for x5 only). Grid (1024, BD); 5 elems/thread.
// ---------------------------------------------------------------------------
__global__ __launch_bounds__(256)
void cost_kernel(const float* __restrict__ x, const float* __restrict__ gt,
                 const float* __restrict__ yobs, const int* __restrict__ mask,
                 float* __restrict__ partial)
{
    const int b  = blockIdx.y;
    const size_t bbase = (size_t)b * VOL;

    float mse = 0.f, dy = 0.f, q = 0.f;
    for (int idx = blockIdx.x * 256 + threadIdx.x; idx < VOL; idx += CBLK * 256) {
        const size_t gi = bbase + idx;
        const int t   = idx / PLANE;
        const int rem = idx - t * PLANE;
        const int i   = rem / NYD;
        const int j   = rem - i * NYD;

        const float v  = x[gi];
        const float g  = gt[gi];
        const float yo = yobs[gi];
        const int   m  = mask[gi];

        mse += (g - v) * (g - v);
        float d = v - yo;
        if (m) dy += d * d;
        float qq = 6.01f * v * v;
        if (t < TD - 1)  qq -= 2.f * v * x[gi + PLANE];
        if (i < NXD - 1) qq -= 2.f * v * x[gi + NYD];
        if (j < NYD - 1) qq -= 2.f * v * x[gi + 1];
        q += qq;
    }

    #pragma unroll
    for (int off = 32; off > 0; off >>= 1) {
        mse += __shfl_xor(mse, off, 64);
        dy  += __shfl_xor(dy,  off, 64);
        q   += __shfl_xor(q,   off, 64);
    }
    __shared__ float red[3][4];
    const int wave = threadIdx.x >> 6;
    const int lane = threadIdx.x & 63;
    if (lane == 0) { red[0][wave] = mse; red[1][wave] = dy; red[2][wave] = q; }
    __syncthreads();
    if (threadIdx.x == 0) {
        float* p = partial + ((size_t)b * CBLK + blockIdx.x) * 3;
        p[0] = red[0][0] + red[0][1] + red[0][2] + red[0][3];
        p[1] = red[1][0] + red[1][1] + red[1][2] + red[1][3];
        p[2] = red[2][0] + red[2][1] + red[2][2] + red[2][3];
    }
}

// cpart layout: [row r=0..4][b=0..3][1024][3].  out cmp_loss [B=4][5][2].
__global__ __launch_bounds__(256)
void finalize_kernel(const float* __restrict__ cpart,
                     float* __restrict__ out)
{
    const int r = blockIdx.x / BD;
    const int b = blockIdx.x - r * BD;
    const float* base = cpart + ((size_t)r * BD + b) * 1024 * 3;
    float mse = 0.f, dy = 0.f, q = 0.f;
    for (int k = threadIdx.x; k < 1024; k += 256) {
        mse += base[k * 3 + 0];
        dy  += base[k * 3 + 1];
        q   += base[k * 3 + 2];
    }
    #pragma unroll
    for (int off = 32; off > 0; off >>= 1) {
        mse += __shfl_xor(mse, off, 64);
        dy  += __shfl_xor(dy,  off, 64);
        q   += __shfl_xor(q,   off, 64);
    }
    __shared__ float red[3][4];
    const int wave = threadIdx.x >> 6;
    const int lane = threadIdx.x & 63;
    if (lane == 0) { red[0][wave] = mse; red[1][wave] = dy; red[2][wave] = q; }
    __syncthreads();
    if (threadIdx.x == 0) {
        float m  = red[0][0] + red[0][1] + red[0][2] + red[0][3];
        float d  = red[1][0] + red[1][1] + red[1][2] + red[1][3];
        float qq = red[2][0] + red[2][1] + red[2][2] + red[2][3];
        out[b * 10 + r * 2 + 0] = m / (float)VOL;
        out[b * 10 + r * 2 + 1] = 1000.f * d + qq;
    }
}

extern "C" void kernel_launch(void* const* d_in, const int* in_sizes, int n_in,
                              void* d_out, int out_size, void* d_ws, size_t ws_size,
                              hipStream_t stream)
{
    const float* gt   = (const float*)d_in[0];
    const float* x0   = (const float*)d_in[1];
    const float* yobs = (const float*)d_in[2];
    const int*   mask = (const int*)d_in[3];
    const float* W1   = (const float*)d_in[4];
    const float* b1   = (const float*)d_in[5];
    const float* W2   = (const float*)d_in[6];
    const float* b2   = (const float*)d_in[7];

    float* out_x    = (float*)d_out;
    float* out_loss = out_x + (size_t)BD * VOL;

    float* wsA      = (float*)d_ws;                   // ping buffer (21 MB)
    float* cpart    = wsA + (size_t)BD * VOL;         // 5*4*1024*3 floats
    __bf16* W1r     = (__bf16*)(cpart + 5 * BD * 1024 * 3);
    __bf16* W2r     = W1r + W1R_ELEMS;
    const size_t PROW = (size_t)BD * 1024 * 3;        // per-row stride

    dim3 pgrid(NXD / 16, NYD / 16, BD), pblock(256);
    dim3 cgrid(CBLK, BD), cblock(256);

    prep_weights<<<dim3(60), dim3(256), 0, stream>>>(W1, W2, W1r, W2r);

    // x1..x4 blended; each phi also computes cost of its INPUT (rows 0..3)
    phi_mfma<<<pgrid, pblock, 0, stream>>>(x0,   W1r, W2r, b1, b2, gt, yobs, mask, out_x, cpart + 0 * PROW, 1);
    phi_mfma<<<pgrid, pblock, 0, stream>>>(out_x,W1r, W2r, b1, b2, gt, yobs, mask, wsA,   cpart + 1 * PROW, 1);
    phi_mfma<<<pgrid, pblock, 0, stream>>>(wsA,  W1r, W2r, b1, b2, gt, yobs, mask, out_x, cpart + 2 * PROW, 1);
    phi_mfma<<<pgrid, pblock, 0, stream>>>(out_x,W1r, W2r, b1, b2, gt, yobs, mask, wsA,   cpart + 3 * PROW, 1);
    // x5 = phi(x4), no blend, no fused cost
    phi_mfma<<<pgrid, pblock, 0, stream>>>(wsA,  W1r, W2r, b1, b2, gt, yobs, mask, out_x, nullptr, 0);
    // cost(x5) -> row 4
    cost_kernel<<<cgrid, cblock, 0, stream>>>(out_x, gt, yobs, mask, cpart + 4 * PROW);

    finalize_kernel<<<dim3(5 * BD), dim3(256), 0, stream>>>(cpart, out_loss);
}

// Round 8
// 745.495 us; speedup vs baseline: 2.5622x; 2.0067x over previous
//
#include <hip/hip_runtime.h>
#include <hip/hip_bf16.h>

#define NXD 512
#define NYD 512
#define TD 5
#define BD 4
#define HIDD 64
#define PLANE (NXD*NYD)      /* 262144 */
#define VOL (TD*PLANE)       /* 1310720 */
#define CBLK 1024            /* cost blocks per batch */

typedef __bf16 bf16x8 __attribute__((ext_vector_type(8)));
typedef __bf16 bf16x4 __attribute__((ext_vector_type(4)));
typedef float  f32x4  __attribute__((ext_vector_type(4)));

// LDS strides: sx 16 B/pixel; sh(strip) 72 B/pixel.
#define SX_PS 16
#define SH_PS 72

// W1r: [kt=3][ch=64][32 bf16]   k = tap*8 + c8   (taps 9..11 zero-padded)
// W2r: [h=2][tap=9][out=16][32] k(within half) = c32; out 5..15 zero
#define W1R_ELEMS (3*64*32)   /* 6144 */
#define W2R_ELEMS (2*9*16*32) /* 9216 */

__global__ __launch_bounds__(256)
void prep_weights(const float* __restrict__ W1, const float* __restrict__ W2,
                  __bf16* __restrict__ W1r, __bf16* __restrict__ W2r)
{
    int id = blockIdx.x * 256 + threadIdx.x;
    if (id < W1R_ELEMS) {
        int kt  = id >> 11;
        int rem = id & 2047;
        int n   = rem >> 5;
        int kk  = rem & 31;
        int k   = kt * 32 + kk;
        int tap = k >> 3, c = k & 7;
        float v = 0.f;
        if (tap <= 8 && c < 5)
            v = W1[(n * 5 + c) * 9 + tap];      // W1 [64][5][3][3]
        W1r[id] = (__bf16)v;
    } else if (id < W1R_ELEMS + W2R_ELEMS) {
        int id2 = id - W1R_ELEMS;
        int h    = id2 / 4608;
        int rem  = id2 - h * 4608;
        int tap  = rem >> 9;
        int rem2 = rem & 511;
        int n    = rem2 >> 5;
        int c    = rem2 & 31;
        float v = 0.f;
        if (n < 5)
            v = W2[(n * HIDD + h * 32 + c) * 9 + tap];  // W2 [5][64][3][3]
        W2r[id2] = (__bf16)v;
    }
}

// ---------------------------------------------------------------------------
// Fused phi (+ optional cost of its INPUT, pure-global).
// A = weights (m = channels), B = activations (n = pixels).
// Per half (32 ch), per strip s in {0,1} (h rows s*8 .. s*8+9):
//   conv1: 12 n-tiles (180 real px of 192), wave does 3; h -> sh strip buffer.
//   conv2: out rows s*8..s*8+7; wave owns rows s*8+wv*2+{0,1}.
// LDS: sx 21x20x16 = 6720 B, sh 180x72 = 12960 B -> 8 blocks/CU by LDS.
// NO min-waves launch_bounds hint: rounds 6/7 showed any waves-hint makes the
// compiler halve the arch-VGPR budget (AGPR split) and spill ~1 GB to scratch.
// Unhinted build allocates ~60 VGPRs -> floor(512/60)=8 waves/SIMD natural.
// ---------------------------------------------------------------------------
__global__ __launch_bounds__(256)
void phi_mfma(const float* __restrict__ xin,
              const __bf16* __restrict__ W1r, const __bf16* __restrict__ W2r,
              const float* __restrict__ b1, const float* __restrict__ b2,
              const float* __restrict__ gt, const float* __restrict__ yobs,
              const int* __restrict__ mask,
              float* __restrict__ xout, float* __restrict__ cpart, int blend)
{
    __shared__ __align__(16) char sx[21 * 20 * SX_PS];  // 6720 B
    __shared__ __align__(16) char sh[180 * SH_PS];      // 12960 B
    __shared__ float red[3][4];

    const int tid   = threadIdx.x;
    const int wv    = tid >> 6;
    const int lane  = tid & 63;
    const int l15   = lane & 15;
    const int quad  = lane >> 4;
    const int b     = blockIdx.z;
    const int gx0   = blockIdx.x * 16;
    const int gy0   = blockIdx.y * 16;
    const float* xb = xin + (size_t)b * VOL;

    // ---- stage x tile 21x20 (halo 2): one b128 write per pixel ----
    for (int p = tid; p < 420; p += 256) {
        const int u  = p / 20;
        const int v  = p - u * 20;
        const int gx = gx0 + u - 2;
        const int gy = gy0 + v - 2;
        bf16x8 pix = {(__bf16)0.f,(__bf16)0.f,(__bf16)0.f,(__bf16)0.f,
                      (__bf16)0.f,(__bf16)0.f,(__bf16)0.f,(__bf16)0.f};
        if (gx >= 0 && gx < NXD && gy >= 0 && gy < NYD) {
            const float* src = xb + (size_t)gx * NYD + gy;
            #pragma unroll
            for (int c = 0; c < TD; ++c) pix[c] = (__bf16)src[(size_t)c * PLANE];
        }
        *(bf16x8*)(sx + p * SX_PS) = pix;
    }

    // ---- fused cost of INPUT x, pure-global (overlaps staging) ----
    if (cpart) {
        const int ti = tid >> 4, tj = tid & 15;
        const int gx = gx0 + ti, gy = gy0 + tj;
        const size_t gbase = (size_t)b * VOL + (size_t)gx * NYD + gy;
        float mse = 0.f, dyv = 0.f, q = 0.f;
        #pragma unroll
        for (int c = 0; c < TD; ++c) {
            const size_t gi = gbase + (size_t)c * PLANE;
            const float vv = xin[gi];
            const float g  = gt[gi];
            const float yo = yobs[gi];
            const int   m  = mask[gi];
            mse += (g - vv) * (g - vv);
            float d = vv - yo;
            if (m) dyv += d * d;
            float nb = 0.f;
            if (c < TD - 1)  nb += xin[gi + PLANE];
            if (gx < NXD - 1) nb += xin[gi + NYD];
            if (gy < NYD - 1) nb += xin[gi + 1];
            q += 6.01f * vv * vv - 2.f * vv * nb;
        }
        #pragma unroll
        for (int off = 32; off > 0; off >>= 1) {
            mse += __shfl_xor(mse, off, 64);
            dyv += __shfl_xor(dyv, off, 64);
            q   += __shfl_xor(q,   off, 64);
        }
        if (lane == 0) { red[0][wv] = mse; red[1][wv] = dyv; red[2][wv] = q; }
    }
    __syncthreads();  // sx ready (+ red ready)
    if (cpart && tid == 0) {
        float* pp = cpart + ((size_t)b * 1024 + blockIdx.y * 32 + blockIdx.x) * 3;
        pp[0] = red[0][0] + red[0][1] + red[0][2] + red[0][3];
        pp[1] = red[1][0] + red[1][1] + red[1][2] + red[1][3];
        pp[2] = red[2][0] + red[2][1] + red[2][2] + red[2][3];
    }

    f32x4 acc2[2][2] = {{{0.f,0.f,0.f,0.f},{0.f,0.f,0.f,0.f}},
                        {{0.f,0.f,0.f,0.f},{0.f,0.f,0.f,0.f}}};

    for (int half = 0; half < 2; ++half) {
        // ---- conv1 A (weight) frags + bias ----
        bf16x8 A1[2][3];
        f32x4  bias1[2];
        #pragma unroll
        for (int mt = 0; mt < 2; ++mt) {
            bias1[mt] = *(const f32x4*)(b1 + half * 32 + mt * 16 + quad * 4);
            #pragma unroll
            for (int kt = 0; kt < 3; ++kt)
                A1[mt][kt] = *(const bf16x8*)(W1r +
                    ((size_t)(kt * 64 + half * 32 + mt * 16 + l15) * 32 + quad * 8));
        }
        // ---- conv2 A (weight) frags for this half ----
        bf16x8 A2[9];
        #pragma unroll
        for (int tap = 0; tap < 9; ++tap)
            A2[tap] = *(const bf16x8*)(W2r +
                ((size_t)((half * 9 + tap) * 16 + l15) * 32 + quad * 8));

        for (int s = 0; s < 2; ++s) {
            if (half | s) __syncthreads();  // prev conv2 reads of sh done

            // ---- conv1 strip: 3 n-tiles per wave ----
            #pragma unroll
            for (int nt = 0; nt < 3; ++nt) {
                const int q  = (wv * 3 + nt) * 16 + l15;  // local px in 192-space
                const int il = q / 18;
                const int j  = q - 18 * il;
                const int rowb = (s * 8 + il) * 20 + j;
                bf16x8 Bx[3];
                #pragma unroll
                for (int kt = 0; kt < 3; ++kt) {
                    int tap = kt * 4 + quad;
                    if (tap > 8) tap = 8;     // pad taps: weights zero, clamp addr
                    Bx[kt] = *(const bf16x8*)(sx + (rowb + (tap / 3) * 20 + tap % 3) * SX_PS);
                }
                #pragma unroll
                for (int mt = 0; mt < 2; ++mt) {
                    f32x4 a = {0.f, 0.f, 0.f, 0.f};
                    #pragma unroll
                    for (int kt = 0; kt < 3; ++kt)
                        a = __builtin_amdgcn_mfma_f32_16x16x32_bf16(
                                A1[mt][kt], Bx[kt], a, 0, 0, 0);
                    if (q < 180) {
                        bf16x4 hv;
                        #pragma unroll
                        for (int r = 0; r < 4; ++r)
                            hv[r] = (__bf16)fmaxf(a[r] + bias1[mt][r], 0.f);
                        *(bf16x4*)(sh + q * SH_PS + (mt * 16 + quad * 4) * 2) = hv;
                    }
                }
            }
            __syncthreads();

            // ---- conv2 strip: row-sum loop, each (row,shift) read once ----
            #pragma unroll
            for (int r = 0; r < 4; ++r) {
                const int rowoff = ((wv * 2 + r) * 18 + l15) * SH_PS + quad * 16;
                #pragma unroll
                for (int tx = 0; tx < 3; ++tx) {
                    const bf16x8 B = *(const bf16x8*)(sh + rowoff + tx * SH_PS);
                    if (r < 3)
                        acc2[s][0] = __builtin_amdgcn_mfma_f32_16x16x32_bf16(
                                         A2[r * 3 + tx], B, acc2[s][0], 0, 0, 0);
                    if (r >= 1)
                        acc2[s][1] = __builtin_amdgcn_mfma_f32_16x16x32_bf16(
                                         A2[(r - 1) * 3 + tx], B, acc2[s][1], 0, 0, 0);
                }
            }
        }
    }

    // ---- epilogue: D row = out-channel (quad*4+reg), col = pixel (l15) ----
    #pragma unroll
    for (int s = 0; s < 2; ++s) {
        #pragma unroll
        for (int m = 0; m < 2; ++m) {
            const int ti2 = s * 8 + wv * 2 + m;
            const size_t rowoff = (size_t)b * VOL + (size_t)(gx0 + ti2) * NYD + (gy0 + l15);
            #pragma unroll
            for (int r = 0; r < 4; ++r) {
                const int ch = quad * 4 + r;
                if (ch < TD) {
                    const size_t off = rowoff + (size_t)ch * PLANE;
                    float o = acc2[s][m][r] + b2[ch];
                    if (blend && mask[off]) o = yobs[off];
                    xout[off] = o;
                }
            }
        }
    }
}

// ---------------------------------------------------------------------------
// Standalone cost (for x5 only). Grid (1024, BD); 5 elems/thread.
// ---------------------------------------------------------------------------
__global__ __launch_bounds__(256)
void cost_kernel(const float* __restrict__ x, const float* __restrict__ gt,
                 const float* __restrict__ yobs, const int* __restrict__ mask,
                 float* __restrict__ partial)
{
    const int b  = blockIdx.y;
    const size_t bbase = (size_t)b * VOL;

    float mse = 0.f, dy = 0.f, q = 0.f;
    for (int idx = blockIdx.x * 256 + threadIdx.x; idx < VOL; idx += CBLK * 256) {
        const size_t gi = bbase + idx;
        const int t   = idx / PLANE;
        const int rem = idx - t * PLANE;
        const int i   = rem / NYD;
        const int j   = rem - i * NYD;

        const float v  = x[gi];
        const float g  = gt[gi];
        const float yo = yobs[gi];
        const int   m  = mask[gi];

        mse += (g - v) * (g - v);
        float d = v - yo;
        if (m) dy += d * d;
        float qq = 6.01f * v * v;
        if (t < TD - 1)  qq -= 2.f * v * x[gi + PLANE];
        if (i < NXD - 1) qq -= 2.f * v * x[gi + NYD];
        if (j < NYD - 1) qq -= 2.f * v * x[gi + 1];
        q += qq;
    }

    #pragma unroll
    for (int off = 32; off > 0; off >>= 1) {
        mse += __shfl_xor(mse, off, 64);
        dy  += __shfl_xor(dy,  off, 64);
        q   += __shfl_xor(q,   off, 64);
    }
    __shared__ float red[3][4];
    const int wave = threadIdx.x >> 6;
    const int lane = threadIdx.x & 63;
    if (lane == 0) { red[0][wave] = mse; red[1][wave] = dy; red[2][wave] = q; }
    __syncthreads();
    if (threadIdx.x == 0) {
        float* p = partial + ((size_t)b * CBLK + blockIdx.x) * 3;
        p[0] = red[0][0] + red[0][1] + red[0][2] + red[0][3];
        p[1] = red[1][0] + red[1][1] + red[1][2] + red[1][3];
        p[2] = red[2][0] + red[2][1] + red[2][2] + red[2][3];
    }
}

// cpart layout: [row r=0..4][b=0..3][1024][3].  out cmp_loss [B=4][5][2].
__global__ __launch_bounds__(256)
void finalize_kernel(const float* __restrict__ cpart,
                     float* __restrict__ out)
{
    const int r = blockIdx.x / BD;
    const int b = blockIdx.x - r * BD;
    const float* base = cpart + ((size_t)r * BD + b) * 1024 * 3;
    float mse = 0.f, dy = 0.f, q = 0.f;
    for (int k = threadIdx.x; k < 1024; k += 256) {
        mse += base[k * 3 + 0];
        dy  += base[k * 3 + 1];
        q   += base[k * 3 + 2];
    }
    #pragma unroll
    for (int off = 32; off > 0; off >>= 1) {
        mse += __shfl_xor(mse, off, 64);
        dy  += __shfl_xor(dy,  off, 64);
        q   += __shfl_xor(q,   off, 64);
    }
    __shared__ float red[3][4];
    const int wave = threadIdx.x >> 6;
    const int lane = threadIdx.x & 63;
    if (lane == 0) { red[0][wave] = mse; red[1][wave] = dy; red[2][wave] = q; }
    __syncthreads();
    if (threadIdx.x == 0) {
        float m  = red[0][0] + red[0][1] + red[0][2] + red[0][3];
        float d  = red[1][0] + red[1][1] + red[1][2] + red[1][3];
        float qq = red[2][0] + red[2][1] + red[2][2] + red[2][3];
        out[b * 10 + r * 2 + 0] = m / (float)VOL;
        out[b * 10 + r * 2 + 1] = 1000.f * d + qq;
    }
}

extern "C" void kernel_launch(void* const* d_in, const int* in_sizes, int n_in,
                              void* d_out, int out_size, void* d_ws, size_t ws_size,
                              hipStream_t stream)
{
    const float* gt   = (const float*)d_in[0];
    const float* x0   = (const float*)d_in[1];
    const float* yobs = (const float*)d_in[2];
    const int*   mask = (const int*)d_in[3];
    const float* W1   = (const float*)d_in[4];
    const float* b1   = (const float*)d_in[5];
    const float* W2   = (const float*)d_in[6];
    const float* b2   = (const float*)d_in[7];

    float* out_x    = (float*)d_out;
    float* out_loss = out_x + (size_t)BD * VOL;

    float* wsA      = (float*)d_ws;                   // ping buffer (21 MB)
    float* cpart    = wsA + (size_t)BD * VOL;         // 5*4*1024*3 floats
    __bf16* W1r     = (__bf16*)(cpart + 5 * BD * 1024 * 3);
    __bf16* W2r     = W1r + W1R_ELEMS;
    const size_t PROW = (size_t)BD * 1024 * 3;        // per-row stride

    dim3 pgrid(NXD / 16, NYD / 16, BD), pblock(256);
    dim3 cgrid(CBLK, BD), cblock(256);

    prep_weights<<<dim3(60), dim3(256), 0, stream>>>(W1, W2, W1r, W2r);

    // x1..x4 blended; each phi also computes cost of its INPUT (rows 0..3)
    phi_mfma<<<pgrid, pblock, 0, stream>>>(x0,   W1r, W2r, b1, b2, gt, yobs, mask, out_x, cpart + 0 * PROW, 1);
    phi_mfma<<<pgrid, pblock, 0, stream>>>(out_x,W1r, W2r, b1, b2, gt, yobs, mask, wsA,   cpart + 1 * PROW, 1);
    phi_mfma<<<pgrid, pblock, 0, stream>>>(wsA,  W1r, W2r, b1, b2, gt, yobs, mask, out_x, cpart + 2 * PROW, 1);
    phi_mfma<<<pgrid, pblock, 0, stream>>>(out_x,W1r, W2r, b1, b2, gt, yobs, mask, wsA,   cpart + 3 * PROW, 1);
    // x5 = phi(x4), no blend, no fused cost
    phi_mfma<<<pgrid, pblock, 0, stream>>>(wsA,  W1r, W2r, b1, b2, gt, yobs, mask, out_x, nullptr, 0);
    // cost(x5) -> row 4
    cost_kernel<<<cgrid, cblock, 0, stream>>>(out_x, gt, yobs, mask, cpart + 4 * PROW);

    finalize_kernel<<<dim3(5 * BD), dim3(256), 0, stream>>>(cpart, out_loss);
}

// Round 9
// 611.693 us; speedup vs baseline: 3.1226x; 1.2187x over previous
//
#include <hip/hip_runtime.h>
#include <hip/hip_bf16.h>

#define NXD 512
#define NYD 512
#define TD 5
#define BD 4
#define HIDD 64
#define PLANE (NXD*NYD)      /* 262144 */
#define VOL (TD*PLANE)       /* 1310720 */
#define CBLK 1024            /* cost blocks per batch */

typedef __bf16 bf16x8 __attribute__((ext_vector_type(8)));
typedef __bf16 bf16x4 __attribute__((ext_vector_type(4)));
typedef float  f32x4  __attribute__((ext_vector_type(4)));

// LDS strides: sx 16 B/pixel; sh 80 B/pixel (16B-aligned, group stride 5,
// coprime with 8).
#define SX_PS 16
#define SH_PS 80

// W1r: [kt=3][ch=64][32 bf16]   k = tap*8 + c8   (taps 9..11 zero-padded)
// W2r: [h=2][tap=9][out=16][32] k(within half) = c32; out 5..15 zero
#define W1R_ELEMS (3*64*32)   /* 6144 */
#define W2R_ELEMS (2*9*16*32) /* 9216 */

__global__ __launch_bounds__(256)
void prep_weights(const float* __restrict__ W1, const float* __restrict__ W2,
                  __bf16* __restrict__ W1r, __bf16* __restrict__ W2r)
{
    int id = blockIdx.x * 256 + threadIdx.x;
    if (id < W1R_ELEMS) {
        int kt  = id >> 11;
        int rem = id & 2047;
        int n   = rem >> 5;
        int kk  = rem & 31;
        int k   = kt * 32 + kk;
        int tap = k >> 3, c = k & 7;
        float v = 0.f;
        if (tap <= 8 && c < 5)
            v = W1[(n * 5 + c) * 9 + tap];      // W1 [64][5][3][3]
        W1r[id] = (__bf16)v;
    } else if (id < W1R_ELEMS + W2R_ELEMS) {
        int id2 = id - W1R_ELEMS;
        int h    = id2 / 4608;
        int rem  = id2 - h * 4608;
        int tap  = rem >> 9;
        int rem2 = rem & 511;
        int n    = rem2 >> 5;
        int c    = rem2 & 31;
        float v = 0.f;
        if (n < 5)
            v = W2[(n * HIDD + h * 32 + c) * 9 + tap];  // W2 [5][64][3][3]
        W2r[id2] = (__bf16)v;
    }
}

// ---------------------------------------------------------------------------
// Fused phi (+ optional cost of its INPUT, pure-global).
// A = weights (m = channels), B = activations (n = pixels).
// Round-5 phase structure (strips of round 8 REGRESSED: 9 barriers of tiny
// phases -> stall-bound 161 us vs 113).  Per half (32 ch):
//   conv1: M=32 (2 m-tiles), N=384 padded px (24 n-tiles, 324 real), K=96.
//   conv2: rolling 6-row x 3-shift register window, 18 reads / 36 MFMA.
// LDS: sx 20x20x16 = 6400 B, sh 324x80 = 25920 B, red 48 B = 32368 B
//   -> 32.5 KB granule -> 5 blocks/CU.  VGPR unhinted ~76 -> 6 wv/SIMD >= 5.
// NO min-waves hint: r6/r7 showed any hint halves arch-VGPR budget -> spill.
// ---------------------------------------------------------------------------
__global__ __launch_bounds__(256)
void phi_mfma(const float* __restrict__ xin,
              const __bf16* __restrict__ W1r, const __bf16* __restrict__ W2r,
              const float* __restrict__ b1, const float* __restrict__ b2,
              const float* __restrict__ gt, const float* __restrict__ yobs,
              const int* __restrict__ mask,
              float* __restrict__ xout, float* __restrict__ cpart, int blend)
{
    __shared__ __align__(16) char sx[20 * 20 * SX_PS];  // 6400 B
    __shared__ __align__(16) char sh[324 * SH_PS];      // 25920 B
    __shared__ float red[3][4];

    const int tid   = threadIdx.x;
    const int wv    = tid >> 6;
    const int lane  = tid & 63;
    const int l15   = lane & 15;
    const int quad  = lane >> 4;
    const int b     = blockIdx.z;
    const int gx0   = blockIdx.x * 16;
    const int gy0   = blockIdx.y * 16;
    const float* xb = xin + (size_t)b * VOL;

    // ---- stage x tile 20x20 (halo 2): one b128 write per pixel ----
    for (int p = tid; p < 400; p += 256) {
        const int u  = p / 20;
        const int v  = p - u * 20;
        const int gx = gx0 + u - 2;
        const int gy = gy0 + v - 2;
        bf16x8 pix = {(__bf16)0.f,(__bf16)0.f,(__bf16)0.f,(__bf16)0.f,
                      (__bf16)0.f,(__bf16)0.f,(__bf16)0.f,(__bf16)0.f};
        if (gx >= 0 && gx < NXD && gy >= 0 && gy < NYD) {
            const float* src = xb + (size_t)gx * NYD + gy;
            #pragma unroll
            for (int c = 0; c < TD; ++c) pix[c] = (__bf16)src[(size_t)c * PLANE];
        }
        *(bf16x8*)(sx + p * SX_PS) = pix;
    }

    // ---- fused cost of INPUT x, pure-global (overlaps staging) ----
    if (cpart) {
        const int ti = tid >> 4, tj = tid & 15;
        const int gx = gx0 + ti, gy = gy0 + tj;
        const size_t gbase = (size_t)b * VOL + (size_t)gx * NYD + gy;
        float mse = 0.f, dyv = 0.f, q = 0.f;
        #pragma unroll
        for (int c = 0; c < TD; ++c) {
            const size_t gi = gbase + (size_t)c * PLANE;
            const float vv = xin[gi];
            const float g  = gt[gi];
            const float yo = yobs[gi];
            const int   m  = mask[gi];
            mse += (g - vv) * (g - vv);
            float d = vv - yo;
            if (m) dyv += d * d;
            float nb = 0.f;
            if (c < TD - 1)  nb += xin[gi + PLANE];
            if (gx < NXD - 1) nb += xin[gi + NYD];
            if (gy < NYD - 1) nb += xin[gi + 1];
            q += 6.01f * vv * vv - 2.f * vv * nb;
        }
        #pragma unroll
        for (int off = 32; off > 0; off >>= 1) {
            mse += __shfl_xor(mse, off, 64);
            dyv += __shfl_xor(dyv, off, 64);
            q   += __shfl_xor(q,   off, 64);
        }
        if (lane == 0) { red[0][wv] = mse; red[1][wv] = dyv; red[2][wv] = q; }
    }
    __syncthreads();  // sx ready (+ red ready)
    if (cpart && tid == 0) {
        float* pp = cpart + ((size_t)b * 1024 + blockIdx.y * 32 + blockIdx.x) * 3;
        pp[0] = red[0][0] + red[0][1] + red[0][2] + red[0][3];
        pp[1] = red[1][0] + red[1][1] + red[1][2] + red[1][3];
        pp[2] = red[2][0] + red[2][1] + red[2][2] + red[2][3];
    }

    f32x4 acc2[4] = {{0.f,0.f,0.f,0.f},{0.f,0.f,0.f,0.f},
                     {0.f,0.f,0.f,0.f},{0.f,0.f,0.f,0.f}};

    for (int half = 0; half < 2; ++half) {
        // ---- conv1 A (weight) frags + bias ----
        bf16x8 A1[2][3];
        f32x4  bias1[2];
        #pragma unroll
        for (int mt = 0; mt < 2; ++mt) {
            bias1[mt] = *(const f32x4*)(b1 + half * 32 + mt * 16 + quad * 4);
            #pragma unroll
            for (int kt = 0; kt < 3; ++kt)
                A1[mt][kt] = *(const bf16x8*)(W1r +
                    ((size_t)(kt * 64 + half * 32 + mt * 16 + l15) * 32 + quad * 8));
        }
        if (half) __syncthreads();   // prev conv2 reads of sh done

        // ---- conv1: 6 pixel n-tiles per wave ----
        #pragma unroll 2
        for (int nt = 0; nt < 6; ++nt) {
            const int pr = (wv * 6 + nt) * 16 + l15;  // padded 384 n-space
            const int p  = pr < 324 ? pr : 323;       // clamp pad region
            const int i  = p / 18;
            const int j  = p - 18 * i;
            const int pb = (i * 20 + j) * SX_PS;
            bf16x8 Bx[3];
            #pragma unroll
            for (int kt = 0; kt < 3; ++kt) {
                int tap = kt * 4 + quad;
                if (tap > 8) tap = 8;         // pad taps: weights zero, clamp addr
                Bx[kt] = *(const bf16x8*)(sx + pb + ((tap / 3) * 20 + tap % 3) * SX_PS);
            }
            #pragma unroll
            for (int mt = 0; mt < 2; ++mt) {
                f32x4 a = {0.f, 0.f, 0.f, 0.f};
                #pragma unroll
                for (int kt = 0; kt < 3; ++kt)
                    a = __builtin_amdgcn_mfma_f32_16x16x32_bf16(
                            A1[mt][kt], Bx[kt], a, 0, 0, 0);
                if (pr < 324) {
                    bf16x4 hv;
                    #pragma unroll
                    for (int r = 0; r < 4; ++r)
                        hv[r] = (__bf16)fmaxf(a[r] + bias1[mt][r], 0.f);
                    *(bf16x4*)(sh + pr * SH_PS + (mt * 16 + quad * 4) * 2) = hv;
                }
            }
        }
        __syncthreads();

        // ---- conv2: rolling 6-row x 3-shift window ----
        bf16x8 A2[9];
        #pragma unroll
        for (int tap = 0; tap < 9; ++tap)
            A2[tap] = *(const bf16x8*)(W2r +
                ((size_t)((half * 9 + tap) * 16 + l15) * 32 + quad * 8));

        const int shbase = (wv * 4 * 18 + l15) * SH_PS + quad * 16;
        bf16x8 R[6][3];
        #pragma unroll
        for (int rr = 0; rr < 3; ++rr)
            #pragma unroll
            for (int tx = 0; tx < 3; ++tx)
                R[rr][tx] = *(const bf16x8*)(sh + shbase + (rr * 18 + tx) * SH_PS);
        #pragma unroll
        for (int m = 0; m < 4; ++m) {
            #pragma unroll
            for (int dy = 0; dy < 3; ++dy)
                #pragma unroll
                for (int tx = 0; tx < 3; ++tx)
                    acc2[m] = __builtin_amdgcn_mfma_f32_16x16x32_bf16(
                                  A2[dy * 3 + tx], R[m + dy][tx], acc2[m], 0, 0, 0);
            if (m < 3) {
                #pragma unroll
                for (int tx = 0; tx < 3; ++tx)
                    R[m + 3][tx] = *(const bf16x8*)(sh + shbase +
                                                    ((m + 3) * 18 + tx) * SH_PS);
            }
        }
    }

    // ---- epilogue: D row = out-channel (quad*4+reg), col = pixel (l15) ----
    #pragma unroll
    for (int m = 0; m < 4; ++m) {
        const int ti2 = wv * 4 + m;
        const size_t rowoff = (size_t)b * VOL + (size_t)(gx0 + ti2) * NYD + (gy0 + l15);
        #pragma unroll
        for (int r = 0; r < 4; ++r) {
            const int ch = quad * 4 + r;
            if (ch < TD) {
                const size_t off = rowoff + (size_t)ch * PLANE;
                float o = acc2[m][r] + b2[ch];
                if (blend && mask[off]) o = yobs[off];
                xout[off] = o;
            }
        }
    }
}

// ---------------------------------------------------------------------------
// Standalone cost (for x5 only). Grid (1024, BD); 5 elems/thread.
// ---------------------------------------------------------------------------
__global__ __launch_bounds__(256)
void cost_kernel(const float* __restrict__ x, const float* __restrict__ gt,
                 const float* __restrict__ yobs, const int* __restrict__ mask,
                 float* __restrict__ partial)
{
    const int b  = blockIdx.y;
    const size_t bbase = (size_t)b * VOL;

    float mse = 0.f, dy = 0.f, q = 0.f;
    for (int idx = blockIdx.x * 256 + threadIdx.x; idx < VOL; idx += CBLK * 256) {
        const size_t gi = bbase + idx;
        const int t   = idx / PLANE;
        const int rem = idx - t * PLANE;
        const int i   = rem / NYD;
        const int j   = rem - i * NYD;

        const float v  = x[gi];
        const float g  = gt[gi];
        const float yo = yobs[gi];
        const int   m  = mask[gi];

        mse += (g - v) * (g - v);
        float d = v - yo;
        if (m) dy += d * d;
        float qq = 6.01f * v * v;
        if (t < TD - 1)  qq -= 2.f * v * x[gi + PLANE];
        if (i < NXD - 1) qq -= 2.f * v * x[gi + NYD];
        if (j < NYD - 1) qq -= 2.f * v * x[gi + 1];
        q += qq;
    }

    #pragma unroll
    for (int off = 32; off > 0; off >>= 1) {
        mse += __shfl_xor(mse, off, 64);
        dy  += __shfl_xor(dy,  off, 64);
        q   += __shfl_xor(q,   off, 64);
    }
    __shared__ float red[3][4];
    const int wave = threadIdx.x >> 6;
    const int lane = threadIdx.x & 63;
    if (lane == 0) { red[0][wave] = mse; red[1][wave] = dy; red[2][wave] = q; }
    __syncthreads();
    if (threadIdx.x == 0) {
        float* p = partial + ((size_t)b * CBLK + blockIdx.x) * 3;
        p[0] = red[0][0] + red[0][1] + red[0][2] + red[0][3];
        p[1] = red[1][0] + red[1][1] + red[1][2] + red[1][3];
        p[2] = red[2][0] + red[2][1] + red[2][2] + red[2][3];
    }
}

// cpart layout: [row r=0..4][b=0..3][1024][3].  out cmp_loss [B=4][5][2].
__global__ __launch_bounds__(256)
void finalize_kernel(const float* __restrict__ cpart,
                     float* __restrict__ out)
{
    const int r = blockIdx.x / BD;
    const int b = blockIdx.x - r * BD;
    const float* base = cpart + ((size_t)r * BD + b) * 1024 * 3;
    float mse = 0.f, dy = 0.f, q = 0.f;
    for (int k = threadIdx.x; k < 1024; k += 256) {
        mse += base[k * 3 + 0];
        dy  += base[k * 3 + 1];
        q   += base[k * 3 + 2];
    }
    #pragma unroll
    for (int off = 32; off > 0; off >>= 1) {
        mse += __shfl_xor(mse, off, 64);
        dy  += __shfl_xor(dy,  off, 64);
        q   += __shfl_xor(q,   off, 64);
    }
    __shared__ float red[3][4];
    const int wave = threadIdx.x >> 6;
    const int lane = threadIdx.x & 63;
    if (lane == 0) { red[0][wave] = mse; red[1][wave] = dy; red[2][wave] = q; }
    __syncthreads();
    if (threadIdx.x == 0) {
        float m  = red[0][0] + red[0][1] + red[0][2] + red[0][3];
        float d  = red[1][0] + red[1][1] + red[1][2] + red[1][3];
        float qq = red[2][0] + red[2][1] + red[2][2] + red[2][3];
        out[b * 10 + r * 2 + 0] = m / (float)VOL;
        out[b * 10 + r * 2 + 1] = 1000.f * d + qq;
    }
}

extern "C" void kernel_launch(void* const* d_in, const int* in_sizes, int n_in,
                              void* d_out, int out_size, void* d_ws, size_t ws_size,
                              hipStream_t stream)
{
    const float* gt   = (const float*)d_in[0];
    const float* x0   = (const float*)d_in[1];
    const float* yobs = (const float*)d_in[2];
    const int*   mask = (const int*)d_in[3];
    const float* W1   = (const float*)d_in[4];
    const float* b1   = (const float*)d_in[5];
    const float* W2   = (const float*)d_in[6];
    const float* b2   = (const float*)d_in[7];

    float* out_x    = (float*)d_out;
    float* out_loss = out_x + (size_t)BD * VOL;

    float* wsA      = (float*)d_ws;                   // ping buffer (21 MB)
    float* cpart    = wsA + (size_t)BD * VOL;         // 5*4*1024*3 floats
    __bf16* W1r     = (__bf16*)(cpart + 5 * BD * 1024 * 3);
    __bf16* W2r     = W1r + W1R_ELEMS;
    const size_t PROW = (size_t)BD * 1024 * 3;        // per-row stride

    dim3 pgrid(NXD / 16, NYD / 16, BD), pblock(256);
    dim3 cgrid(CBLK, BD), cblock(256);

    prep_weights<<<dim3(60), dim3(256), 0, stream>>>(W1, W2, W1r, W2r);

    // x1..x4 blended; each phi also computes cost of its INPUT (rows 0..3)
    phi_mfma<<<pgrid, pblock, 0, stream>>>(x0,   W1r, W2r, b1, b2, gt, yobs, mask, out_x, cpart + 0 * PROW, 1);
    phi_mfma<<<pgrid, pblock, 0, stream>>>(out_x,W1r, W2r, b1, b2, gt, yobs, mask, wsA,   cpart + 1 * PROW, 1);
    phi_mfma<<<pgrid, pblock, 0, stream>>>(wsA,  W1r, W2r, b1, b2, gt, yobs, mask, out_x, cpart + 2 * PROW, 1);
    phi_mfma<<<pgrid, pblock, 0, stream>>>(out_x,W1r, W2r, b1, b2, gt, yobs, mask, wsA,   cpart + 3 * PROW, 1);
    // x5 = phi(x4), no blend, no fused cost
    phi_mfma<<<pgrid, pblock, 0, stream>>>(wsA,  W1r, W2r, b1, b2, gt, yobs, mask, out_x, nullptr, 0);
    // cost(x5) -> row 4
    cost_kernel<<<cgrid, cblock, 0, stream>>>(out_x, gt, yobs, mask, cpart + 4 * PROW);

    finalize_kernel<<<dim3(5 * BD), dim3(256), 0, stream>>>(cpart, out_loss);
}